// Round 2
// baseline (649.667 us; speedup 1.0000x reference)
//
#include <hip/hip_runtime.h>

// Attention_37074157699274 : fused qkv-proj + 8-head attention (n=32,d=64) + out-proj
// R3: fragment-packed weights (coalesced 1KiB wave loads), distance-2 double-buffered
// weight prefetch, non-temporal x/out streaming to protect L2 weight residency.
// R4: occupancy push 2->3 blocks/CU. Xs staging buffer overlays the wave-private pool
// (dead after xa-fragment hoist; extra barrier), vT tightened [64][40]->[64][32].
// LDS 74240->53248. Plain output stores (let L2 merge 64B half-line quad writes).
// R5: FIX R4's OOB swizzle. vswz must stay inside the 32-elem row: use
// ((row>>1)&3)<<3 (== ((l16>>1)&3)<<3 for every nt) instead of (l16&7)<<3 which
// reached 56 and spilled into neighboring rows / the next wave's qs. Corrected
// swizzle spreads vT writes over all 32 banks (4 lanes/bank, optimal); reads
// stay 16B-aligned and evenly spread (8 lanes/16B-slot = throughput floor).

typedef __bf16 bf16x8 __attribute__((ext_vector_type(8)));
typedef __bf16 bf16x4 __attribute__((ext_vector_type(4)));
typedef float f32x4 __attribute__((ext_vector_type(4)));
typedef float f32x4v __attribute__((ext_vector_type(4)));

__device__ __forceinline__ f32x4 mfma16(bf16x8 a, bf16x8 b, f32x4 c) {
  return __builtin_amdgcn_mfma_f32_16x16x32_bf16(a, b, c, 0, 0, 0);
}

// ws: [0,786432) WqkvP bf16 packed frags ; [786432,1048576) WoutP bf16 packed frags
// WqkvP: frag t = (combo*8 + kk)*64 + lane, combo = (mat*8+h)*4+nt, 8 ele each:
//   ele j = Wqkv[k][n], n = mat*512+h*64+nt*16+(lane&15), k = kk*32+(lane>>4)*8+j
// WoutP: frag t = (ntile*16 + kk)*64 + lane:
//   ele j = Wout[k][n], n = ntile*16+(lane&15), k = kk*32+(lane>>4)*8+j
__global__ __launch_bounds__(256) void prep_weights(const float* __restrict__ Wqkv,
                                                    const float* __restrict__ Wout,
                                                    __bf16* __restrict__ WqkvP,
                                                    __bf16* __restrict__ WoutP) {
  int t = blockIdx.x * 256 + threadIdx.x;
  if (t < 49152) {
    int lane = t & 63, rest = t >> 6;
    int kk = rest & 7, combo = rest >> 3;
    int nt = combo & 3, mh = combo >> 2;
    int h = mh & 7, mat = mh >> 3;
    int l16 = lane & 15, quad = lane >> 4;
    int n = mat * 512 + h * 64 + nt * 16 + l16;
    int k0 = kk * 32 + quad * 8;
    __bf16* dst = WqkvP + (size_t)t * 8;
#pragma unroll
    for (int j = 0; j < 8; j++) dst[j] = (__bf16)Wqkv[(size_t)(k0 + j) * 1536 + n];
  }
  int t2 = t - 49152;
  if (t2 >= 0 && t2 < 16384) {
    int lane = t2 & 63, rest = t2 >> 6;
    int kk = rest & 15, ntile = rest >> 4;
    int l16 = lane & 15, quad = lane >> 4;
    int n = ntile * 16 + l16;
    int k0 = kk * 32 + quad * 8;
    __bf16* dst = WoutP + (size_t)t2 * 8;
#pragma unroll
    for (int j = 0; j < 8; j++) dst[j] = (__bf16)Wout[(size_t)(k0 + j) * 256 + n];
  }
}

__global__ __launch_bounds__(256, 3) void attn_fused(const float* __restrict__ x,
                                                     const __bf16* __restrict__ WqkvP,
                                                     const __bf16* __restrict__ WoutP,
                                                     const float* __restrict__ b_out,
                                                     float* __restrict__ out) {
  // Single pool, 53248 B total -> 3 blocks/CU.
  // Phase A (staging):   Xs overlay [32][264] = 8448 ele
  // Phase B (attention): per-wave {qs[32][72], ks[32][72], vT[64][32] swizzled} = 6656 ele
  // Phase C (out-proj):  Os overlay [32][520] = 16640 ele
  __shared__ __align__(16) __bf16 pool[4 * 6656];

  const int tid  = threadIdx.x;
  const int wave = tid >> 6;
  const int lane = tid & 63;
  const int quad = lane >> 4;
  const int l16  = lane & 15;
  const int bp   = blockIdx.x;

  __bf16* qs = pool + wave * 6656;  // [32][72]  (reused as P scratch)
  __bf16* ks = qs + 2304;           // [32][72]
  __bf16* vT = ks + 2304;           // [64][32]  v transposed, XOR-swizzled
  __bf16* Xs = pool;                // [32][264] staging overlay (dead after hoist)
  __bf16* Os = pool;                // [32][520] after barrier 2 (overlays pool)

  // ---- stage X tile -> LDS bf16 (non-temporal: read-once stream) ----
  const f32x4v* xg = (const f32x4v*)(x + (size_t)bp * 32 * 256);
  for (int i = tid; i < 32 * 64; i += 256) {
    int row = i >> 6, c4 = i & 63;
    f32x4v v = __builtin_nontemporal_load(xg + i);
    bf16x4 pk;
    pk[0] = (__bf16)v[0]; pk[1] = (__bf16)v[1]; pk[2] = (__bf16)v[2]; pk[3] = (__bf16)v[3];
    *(bf16x4*)(&Xs[row * 264 + c4 * 4]) = pk;
  }
  __syncthreads();  // barrier 1: Xs staged

  // ---- weight-fragment load helpers (each: 8 perfectly-coalesced 1KiB wave loads) ----
  bf16x8 bb[2][8];
  auto load_qkv = [&](int c, bf16x8* dst) {
    int hloc = wave * 2 + (c >= 12 ? 1 : 0);
    int r = (c >= 12) ? c - 12 : c;
    int mat = r >> 2, nt = r & 3;
    const __bf16* base = WqkvP + ((size_t)((mat * 8 + hloc) * 4 + nt)) * 4096 + lane * 8;
#pragma unroll
    for (int kk = 0; kk < 8; kk++) dst[kk] = *(const bf16x8*)(base + kk * 512);
  };

  load_qkv(0, bb[0]);
  load_qkv(1, bb[1]);

  // ---- hoist X A-fragments (reused by all 24 qkv combos) ----
  bf16x8 xa0[8], xa1[8];
#pragma unroll
  for (int kk = 0; kk < 8; kk++) {
    xa0[kk] = *(const bf16x8*)(&Xs[l16 * 264 + kk * 32 + quad * 8]);
    xa1[kk] = *(const bf16x8*)(&Xs[(16 + l16) * 264 + kk * 32 + quad * 8]);
  }
  __syncthreads();  // barrier 1b: all waves done reading Xs before pool is overwritten

  const f32x4 zero = {0.f, 0.f, 0.f, 0.f};
  // vT XOR-swizzle term: f(row) = ((row>>1)&3)<<3 with row = nt*16+l16.
  // nt*16 ≡ 0 mod 4 after >>1, so f(row) == ((l16>>1)&3)<<3 for all nt.
  // Values {0,8,16,24}: stays inside the 32-elem row, keeps 16B alignment.
  const int vswz = ((l16 >> 1) & 3) << 3;
  bf16x4 obf[2][2][4];  // O output [hh][mt][nt] in regs until Os write

#pragma unroll
  for (int hh = 0; hh < 2; hh++) {
#pragma unroll
    for (int r = 0; r < 12; r++) {
      const int c = hh * 12 + r;
      const int mat = r >> 2, nt = r & 3;
      f32x4 a0 = zero, a1 = zero;
#pragma unroll
      for (int kk = 0; kk < 8; kk++) {
        a0 = mfma16(xa0[kk], bb[c & 1][kk], a0);
        a1 = mfma16(xa1[kk], bb[c & 1][kk], a1);
      }
      if (c + 2 < 24) load_qkv(c + 2, bb[c & 1]);  // distance-2 prefetch (after last use)
      if (mat == 0) {  // q — fold softmax scale 1/8
#pragma unroll
        for (int rr = 0; rr < 4; rr++) {
          qs[(quad * 4 + rr) * 72 + nt * 16 + l16]      = (__bf16)(a0[rr] * 0.125f);
          qs[(16 + quad * 4 + rr) * 72 + nt * 16 + l16] = (__bf16)(a1[rr] * 0.125f);
        }
      } else if (mat == 1) {
#pragma unroll
        for (int rr = 0; rr < 4; rr++) {
          ks[(quad * 4 + rr) * 72 + nt * 16 + l16]      = (__bf16)a0[rr];
          ks[(16 + quad * 4 + rr) * 72 + nt * 16 + l16] = (__bf16)a1[rr];
        }
      } else {  // v transposed: vT[d][token], token cols XOR-swizzled by ((d>>1)&3)<<3
        bf16x4 p0, p1;
#pragma unroll
        for (int rr = 0; rr < 4; rr++) { p0[rr] = (__bf16)a0[rr]; p1[rr] = (__bf16)a1[rr]; }
        int rb = (nt * 16 + l16) * 32;
        *(bf16x4*)(&vT[rb + ((quad * 4) ^ vswz)])      = p0;
        *(bf16x4*)(&vT[rb + ((16 + quad * 4) ^ vswz)]) = p1;
      }
    }

    // ---- S = q @ k^T (scale folded into q), wave-private ----
    f32x4 s[2][2] = {{zero, zero}, {zero, zero}};
#pragma unroll
    for (int kk = 0; kk < 2; kk++) {
      bf16x8 a0 = *(const bf16x8*)(&qs[l16 * 72 + kk * 32 + quad * 8]);
      bf16x8 a1 = *(const bf16x8*)(&qs[(16 + l16) * 72 + kk * 32 + quad * 8]);
      bf16x8 b0 = *(const bf16x8*)(&ks[l16 * 72 + kk * 32 + quad * 8]);
      bf16x8 b1 = *(const bf16x8*)(&ks[(16 + l16) * 72 + kk * 32 + quad * 8]);
      s[0][0] = mfma16(a0, b0, s[0][0]);
      s[0][1] = mfma16(a0, b1, s[0][1]);
      s[1][0] = mfma16(a1, b0, s[1][0]);
      s[1][1] = mfma16(a1, b1, s[1][1]);
    }

    // ---- in-register softmax: row i lives in the 16 lanes of one quad ----
    float mx[2][4], sm[2][4], e[2][2][4];
#pragma unroll
    for (int mt = 0; mt < 2; mt++)
#pragma unroll
      for (int rr = 0; rr < 4; rr++) mx[mt][rr] = fmaxf(s[mt][0][rr], s[mt][1][rr]);
#pragma unroll
    for (int mask = 1; mask < 16; mask <<= 1)
#pragma unroll
      for (int mt = 0; mt < 2; mt++)
#pragma unroll
        for (int rr = 0; rr < 4; rr++) mx[mt][rr] = fmaxf(mx[mt][rr], __shfl_xor(mx[mt][rr], mask));
#pragma unroll
    for (int mt = 0; mt < 2; mt++)
#pragma unroll
      for (int rr = 0; rr < 4; rr++) {
        e[mt][0][rr] = __expf(s[mt][0][rr] - mx[mt][rr]);
        e[mt][1][rr] = __expf(s[mt][1][rr] - mx[mt][rr]);
        sm[mt][rr] = e[mt][0][rr] + e[mt][1][rr];
      }
#pragma unroll
    for (int mask = 1; mask < 16; mask <<= 1)
#pragma unroll
      for (int mt = 0; mt < 2; mt++)
#pragma unroll
        for (int rr = 0; rr < 4; rr++) sm[mt][rr] += __shfl_xor(sm[mt][rr], mask);

    // ---- P -> LDS (C-layout, reuse qs) -> reread in A-layout ----
#pragma unroll
    for (int mt = 0; mt < 2; mt++) {
      float inv0 = 1.f / sm[mt][0], inv1 = 1.f / sm[mt][1], inv2 = 1.f / sm[mt][2], inv3 = 1.f / sm[mt][3];
#pragma unroll
      for (int nt = 0; nt < 2; nt++) {
        qs[(mt * 16 + quad * 4 + 0) * 72 + nt * 16 + l16] = (__bf16)(e[mt][nt][0] * inv0);
        qs[(mt * 16 + quad * 4 + 1) * 72 + nt * 16 + l16] = (__bf16)(e[mt][nt][1] * inv1);
        qs[(mt * 16 + quad * 4 + 2) * 72 + nt * 16 + l16] = (__bf16)(e[mt][nt][2] * inv2);
        qs[(mt * 16 + quad * 4 + 3) * 72 + nt * 16 + l16] = (__bf16)(e[mt][nt][3] * inv3);
      }
    }
    bf16x8 pa0 = *(const bf16x8*)(&qs[l16 * 72 + quad * 8]);
    bf16x8 pa1 = *(const bf16x8*)(&qs[(16 + l16) * 72 + quad * 8]);

    // ---- O = P @ v ----
#pragma unroll
    for (int nt = 0; nt < 4; nt++) {
      bf16x8 b = *(const bf16x8*)(&vT[(nt * 16 + l16) * 32 + ((quad * 8) ^ vswz)]);
      f32x4 o0 = mfma16(pa0, b, zero);
      f32x4 o1 = mfma16(pa1, b, zero);
#pragma unroll
      for (int rr = 0; rr < 4; rr++) {
        obf[hh][0][nt][rr] = (__bf16)o0[rr];
        obf[hh][1][nt][rr] = (__bf16)o1[rr];
      }
    }
  }

  // ---- prefetch first two out-proj weight batches before the barriers ----
  bf16x8 wb[2][8];
  auto load_wout = [&](int b, bf16x8* dst) {
    int g = b >> 1, ntile = wave + g * 4, kk0 = (b & 1) * 8;
    const __bf16* base = WoutP + ((size_t)(ntile * 16 + kk0) * 64 + lane) * 8;
#pragma unroll
    for (int j = 0; j < 8; j++) dst[j] = *(const bf16x8*)(base + j * 512);
  };
  load_wout(0, wb[0]);
  load_wout(1, wb[1]);

  __syncthreads();  // barrier 2: waves done with private pool regions

  // ---- write O (all heads) into Os[32][520] overlaying pool ----
#pragma unroll
  for (int hh = 0; hh < 2; hh++) {
    int h = wave * 2 + hh;
#pragma unroll
    for (int mt = 0; mt < 2; mt++)
#pragma unroll
      for (int nt = 0; nt < 4; nt++)
#pragma unroll
        for (int rr = 0; rr < 4; rr++)
          Os[(mt * 16 + quad * 4 + rr) * 520 + h * 64 + nt * 16 + l16] = obf[hh][mt][nt][rr];
  }
  __syncthreads();  // barrier 3

  // ---- out = O @ W_out + b : 8 pipelined weight batches ----
  f32x4 outacc[4][2];
#pragma unroll
  for (int g = 0; g < 4; g++) { outacc[g][0] = zero; outacc[g][1] = zero; }
#pragma unroll
  for (int b = 0; b < 8; b++) {
    int g = b >> 1, kk0 = (b & 1) * 8;
#pragma unroll
    for (int j = 0; j < 8; j++) {
      int kk = kk0 + j;
      bf16x8 a0 = *(const bf16x8*)(&Os[l16 * 520 + kk * 32 + quad * 8]);
      bf16x8 a1 = *(const bf16x8*)(&Os[(16 + l16) * 520 + kk * 32 + quad * 8]);
      outacc[g][0] = mfma16(a0, wb[b & 1][j], outacc[g][0]);
      outacc[g][1] = mfma16(a1, wb[b & 1][j], outacc[g][1]);
    }
    if (b + 2 < 8) load_wout(b + 2, wb[b & 1]);  // distance-2, after last use
  }

  // ---- epilogue: bias + store (plain stores: let L2 merge 64B half-lines) ----
  float* og = out + (size_t)bp * 32 * 256;
#pragma unroll
  for (int g = 0; g < 4; g++) {
    int ntile = wave + g * 4;
    float bias = b_out[ntile * 16 + l16];
#pragma unroll
    for (int mt = 0; mt < 2; mt++) {
      f32x4 a = outacc[g][mt];
#pragma unroll
      for (int rr = 0; rr < 4; rr++)
        og[(mt * 16 + quad * 4 + rr) * 256 + ntile * 16 + l16] = a[rr] + bias;
    }
  }
}

extern "C" void kernel_launch(void* const* d_in, const int* in_sizes, int n_in,
                              void* d_out, int out_size, void* d_ws, size_t ws_size,
                              hipStream_t stream) {
  const float* x    = (const float*)d_in[0];
  const float* Wqkv = (const float*)d_in[1];
  const float* Wout = (const float*)d_in[2];
  const float* bout = (const float*)d_in[3];
  float* out = (float*)d_out;

  __bf16* WqkvP = (__bf16*)d_ws;
  __bf16* WoutP = (__bf16*)((char*)d_ws + (size_t)1536 * 256 * 2);

  prep_weights<<<256, 256, 0, stream>>>(Wqkv, Wout, WqkvP, WoutP);
  attn_fused<<<4096, 256, 0, stream>>>(x, WqkvP, WoutP, bout, out);
}

// Round 3
// 408.406 us; speedup vs baseline: 1.5907x; 1.5907x over previous
//
#include <hip/hip_runtime.h>

// Attention_37074157699274 : fused qkv-proj + 8-head attention (n=32,d=64) + out-proj
// R3: fragment-packed weights (coalesced 1KiB wave loads), distance-2 double-buffered
// weight prefetch, non-temporal x streaming to protect L2 weight residency.
// R4/R5: LDS 74240->53248 (Xs overlays pool, vT tightened to [64][32] + in-row XOR
// swizzle) -> 3 blocks/CU LDS-limited. Plain output stores.
// R6: FIX R5's spill catastrophe. __launch_bounds__(256,3) drove the allocator to an
// 84-VGPR budget (6 waves/EU target) and spilled ~35 regs/lane -> 1.5 GB/dispatch
// scratch traffic, 500us. Revert to (256,2): allocator lands ~120 VGPR (<=170), so
// occupancy is LDS-limited at 3 blocks/CU — same occupancy win, zero spills.

typedef __bf16 bf16x8 __attribute__((ext_vector_type(8)));
typedef __bf16 bf16x4 __attribute__((ext_vector_type(4)));
typedef float f32x4 __attribute__((ext_vector_type(4)));
typedef float f32x4v __attribute__((ext_vector_type(4)));

__device__ __forceinline__ f32x4 mfma16(bf16x8 a, bf16x8 b, f32x4 c) {
  return __builtin_amdgcn_mfma_f32_16x16x32_bf16(a, b, c, 0, 0, 0);
}

// ws: [0,786432) WqkvP bf16 packed frags ; [786432,1048576) WoutP bf16 packed frags
// WqkvP: frag t = (combo*8 + kk)*64 + lane, combo = (mat*8+h)*4+nt, 8 ele each:
//   ele j = Wqkv[k][n], n = mat*512+h*64+nt*16+(lane&15), k = kk*32+(lane>>4)*8+j
// WoutP: frag t = (ntile*16 + kk)*64 + lane:
//   ele j = Wout[k][n], n = ntile*16+(lane&15), k = kk*32+(lane>>4)*8+j
__global__ __launch_bounds__(256) void prep_weights(const float* __restrict__ Wqkv,
                                                    const float* __restrict__ Wout,
                                                    __bf16* __restrict__ WqkvP,
                                                    __bf16* __restrict__ WoutP) {
  int t = blockIdx.x * 256 + threadIdx.x;
  if (t < 49152) {
    int lane = t & 63, rest = t >> 6;
    int kk = rest & 7, combo = rest >> 3;
    int nt = combo & 3, mh = combo >> 2;
    int h = mh & 7, mat = mh >> 3;
    int l16 = lane & 15, quad = lane >> 4;
    int n = mat * 512 + h * 64 + nt * 16 + l16;
    int k0 = kk * 32 + quad * 8;
    __bf16* dst = WqkvP + (size_t)t * 8;
#pragma unroll
    for (int j = 0; j < 8; j++) dst[j] = (__bf16)Wqkv[(size_t)(k0 + j) * 1536 + n];
  }
  int t2 = t - 49152;
  if (t2 >= 0 && t2 < 16384) {
    int lane = t2 & 63, rest = t2 >> 6;
    int kk = rest & 15, ntile = rest >> 4;
    int l16 = lane & 15, quad = lane >> 4;
    int n = ntile * 16 + l16;
    int k0 = kk * 32 + quad * 8;
    __bf16* dst = WoutP + (size_t)t2 * 8;
#pragma unroll
    for (int j = 0; j < 8; j++) dst[j] = (__bf16)Wout[(size_t)(k0 + j) * 256 + n];
  }
}

__global__ __launch_bounds__(256, 2) void attn_fused(const float* __restrict__ x,
                                                     const __bf16* __restrict__ WqkvP,
                                                     const __bf16* __restrict__ WoutP,
                                                     const float* __restrict__ b_out,
                                                     float* __restrict__ out) {
  // Single pool, 53248 B total -> 3 blocks/CU (LDS-limited; VGPR ~120 allows 4).
  // Phase A (staging):   Xs overlay [32][264] = 8448 ele
  // Phase B (attention): per-wave {qs[32][72], ks[32][72], vT[64][32] swizzled} = 6656 ele
  // Phase C (out-proj):  Os overlay [32][520] = 16640 ele
  __shared__ __align__(16) __bf16 pool[4 * 6656];

  const int tid  = threadIdx.x;
  const int wave = tid >> 6;
  const int lane = tid & 63;
  const int quad = lane >> 4;
  const int l16  = lane & 15;
  const int bp   = blockIdx.x;

  __bf16* qs = pool + wave * 6656;  // [32][72]  (reused as P scratch)
  __bf16* ks = qs + 2304;           // [32][72]
  __bf16* vT = ks + 2304;           // [64][32]  v transposed, XOR-swizzled
  __bf16* Xs = pool;                // [32][264] staging overlay (dead after hoist)
  __bf16* Os = pool;                // [32][520] after barrier 2 (overlays pool)

  // ---- stage X tile -> LDS bf16 (non-temporal: read-once stream) ----
  const f32x4v* xg = (const f32x4v*)(x + (size_t)bp * 32 * 256);
  for (int i = tid; i < 32 * 64; i += 256) {
    int row = i >> 6, c4 = i & 63;
    f32x4v v = __builtin_nontemporal_load(xg + i);
    bf16x4 pk;
    pk[0] = (__bf16)v[0]; pk[1] = (__bf16)v[1]; pk[2] = (__bf16)v[2]; pk[3] = (__bf16)v[3];
    *(bf16x4*)(&Xs[row * 264 + c4 * 4]) = pk;
  }
  __syncthreads();  // barrier 1: Xs staged

  // ---- weight-fragment load helpers (each: 8 perfectly-coalesced 1KiB wave loads) ----
  bf16x8 bb[2][8];
  auto load_qkv = [&](int c, bf16x8* dst) {
    int hloc = wave * 2 + (c >= 12 ? 1 : 0);
    int r = (c >= 12) ? c - 12 : c;
    int mat = r >> 2, nt = r & 3;
    const __bf16* base = WqkvP + ((size_t)((mat * 8 + hloc) * 4 + nt)) * 4096 + lane * 8;
#pragma unroll
    for (int kk = 0; kk < 8; kk++) dst[kk] = *(const bf16x8*)(base + kk * 512);
  };

  load_qkv(0, bb[0]);
  load_qkv(1, bb[1]);

  // ---- hoist X A-fragments (reused by all 24 qkv combos) ----
  bf16x8 xa0[8], xa1[8];
#pragma unroll
  for (int kk = 0; kk < 8; kk++) {
    xa0[kk] = *(const bf16x8*)(&Xs[l16 * 264 + kk * 32 + quad * 8]);
    xa1[kk] = *(const bf16x8*)(&Xs[(16 + l16) * 264 + kk * 32 + quad * 8]);
  }
  __syncthreads();  // barrier 1b: all waves done reading Xs before pool is overwritten

  const f32x4 zero = {0.f, 0.f, 0.f, 0.f};
  // vT XOR-swizzle term: f(row) = ((row>>1)&3)<<3 with row = nt*16+l16.
  // nt*16 ≡ 0 mod 4 after >>1, so f(row) == ((l16>>1)&3)<<3 for all nt.
  // Values {0,8,16,24}: stays inside the 32-elem row, keeps 16B alignment.
  const int vswz = ((l16 >> 1) & 3) << 3;
  bf16x4 obf[2][2][4];  // O output [hh][mt][nt] in regs until Os write

#pragma unroll
  for (int hh = 0; hh < 2; hh++) {
#pragma unroll
    for (int r = 0; r < 12; r++) {
      const int c = hh * 12 + r;
      const int mat = r >> 2, nt = r & 3;
      f32x4 a0 = zero, a1 = zero;
#pragma unroll
      for (int kk = 0; kk < 8; kk++) {
        a0 = mfma16(xa0[kk], bb[c & 1][kk], a0);
        a1 = mfma16(xa1[kk], bb[c & 1][kk], a1);
      }
      if (c + 2 < 24) load_qkv(c + 2, bb[c & 1]);  // distance-2 prefetch (after last use)
      if (mat == 0) {  // q — fold softmax scale 1/8
#pragma unroll
        for (int rr = 0; rr < 4; rr++) {
          qs[(quad * 4 + rr) * 72 + nt * 16 + l16]      = (__bf16)(a0[rr] * 0.125f);
          qs[(16 + quad * 4 + rr) * 72 + nt * 16 + l16] = (__bf16)(a1[rr] * 0.125f);
        }
      } else if (mat == 1) {
#pragma unroll
        for (int rr = 0; rr < 4; rr++) {
          ks[(quad * 4 + rr) * 72 + nt * 16 + l16]      = (__bf16)a0[rr];
          ks[(16 + quad * 4 + rr) * 72 + nt * 16 + l16] = (__bf16)a1[rr];
        }
      } else {  // v transposed: vT[d][token], token cols XOR-swizzled by ((d>>1)&3)<<3
        bf16x4 p0, p1;
#pragma unroll
        for (int rr = 0; rr < 4; rr++) { p0[rr] = (__bf16)a0[rr]; p1[rr] = (__bf16)a1[rr]; }
        int rb = (nt * 16 + l16) * 32;
        *(bf16x4*)(&vT[rb + ((quad * 4) ^ vswz)])      = p0;
        *(bf16x4*)(&vT[rb + ((16 + quad * 4) ^ vswz)]) = p1;
      }
    }

    // ---- S = q @ k^T (scale folded into q), wave-private ----
    f32x4 s[2][2] = {{zero, zero}, {zero, zero}};
#pragma unroll
    for (int kk = 0; kk < 2; kk++) {
      bf16x8 a0 = *(const bf16x8*)(&qs[l16 * 72 + kk * 32 + quad * 8]);
      bf16x8 a1 = *(const bf16x8*)(&qs[(16 + l16) * 72 + kk * 32 + quad * 8]);
      bf16x8 b0 = *(const bf16x8*)(&ks[l16 * 72 + kk * 32 + quad * 8]);
      bf16x8 b1 = *(const bf16x8*)(&ks[(16 + l16) * 72 + kk * 32 + quad * 8]);
      s[0][0] = mfma16(a0, b0, s[0][0]);
      s[0][1] = mfma16(a0, b1, s[0][1]);
      s[1][0] = mfma16(a1, b0, s[1][0]);
      s[1][1] = mfma16(a1, b1, s[1][1]);
    }

    // ---- in-register softmax: row i lives in the 16 lanes of one quad ----
    float mx[2][4], sm[2][4], e[2][2][4];
#pragma unroll
    for (int mt = 0; mt < 2; mt++)
#pragma unroll
      for (int rr = 0; rr < 4; rr++) mx[mt][rr] = fmaxf(s[mt][0][rr], s[mt][1][rr]);
#pragma unroll
    for (int mask = 1; mask < 16; mask <<= 1)
#pragma unroll
      for (int mt = 0; mt < 2; mt++)
#pragma unroll
        for (int rr = 0; rr < 4; rr++) mx[mt][rr] = fmaxf(mx[mt][rr], __shfl_xor(mx[mt][rr], mask));
#pragma unroll
    for (int mt = 0; mt < 2; mt++)
#pragma unroll
      for (int rr = 0; rr < 4; rr++) {
        e[mt][0][rr] = __expf(s[mt][0][rr] - mx[mt][rr]);
        e[mt][1][rr] = __expf(s[mt][1][rr] - mx[mt][rr]);
        sm[mt][rr] = e[mt][0][rr] + e[mt][1][rr];
      }
#pragma unroll
    for (int mask = 1; mask < 16; mask <<= 1)
#pragma unroll
      for (int mt = 0; mt < 2; mt++)
#pragma unroll
        for (int rr = 0; rr < 4; rr++) sm[mt][rr] += __shfl_xor(sm[mt][rr], mask);

    // ---- P -> LDS (C-layout, reuse qs) -> reread in A-layout ----
#pragma unroll
    for (int mt = 0; mt < 2; mt++) {
      float inv0 = 1.f / sm[mt][0], inv1 = 1.f / sm[mt][1], inv2 = 1.f / sm[mt][2], inv3 = 1.f / sm[mt][3];
#pragma unroll
      for (int nt = 0; nt < 2; nt++) {
        qs[(mt * 16 + quad * 4 + 0) * 72 + nt * 16 + l16] = (__bf16)(e[mt][nt][0] * inv0);
        qs[(mt * 16 + quad * 4 + 1) * 72 + nt * 16 + l16] = (__bf16)(e[mt][nt][1] * inv1);
        qs[(mt * 16 + quad * 4 + 2) * 72 + nt * 16 + l16] = (__bf16)(e[mt][nt][2] * inv2);
        qs[(mt * 16 + quad * 4 + 3) * 72 + nt * 16 + l16] = (__bf16)(e[mt][nt][3] * inv3);
      }
    }
    bf16x8 pa0 = *(const bf16x8*)(&qs[l16 * 72 + quad * 8]);
    bf16x8 pa1 = *(const bf16x8*)(&qs[(16 + l16) * 72 + quad * 8]);

    // ---- O = P @ v ----
#pragma unroll
    for (int nt = 0; nt < 4; nt++) {
      bf16x8 b = *(const bf16x8*)(&vT[(nt * 16 + l16) * 32 + ((quad * 8) ^ vswz)]);
      f32x4 o0 = mfma16(pa0, b, zero);
      f32x4 o1 = mfma16(pa1, b, zero);
#pragma unroll
      for (int rr = 0; rr < 4; rr++) {
        obf[hh][0][nt][rr] = (__bf16)o0[rr];
        obf[hh][1][nt][rr] = (__bf16)o1[rr];
      }
    }
  }

  // ---- prefetch first two out-proj weight batches before the barriers ----
  bf16x8 wb[2][8];
  auto load_wout = [&](int b, bf16x8* dst) {
    int g = b >> 1, ntile = wave + g * 4, kk0 = (b & 1) * 8;
    const __bf16* base = WoutP + ((size_t)(ntile * 16 + kk0) * 64 + lane) * 8;
#pragma unroll
    for (int j = 0; j < 8; j++) dst[j] = *(const bf16x8*)(base + j * 512);
  };
  load_wout(0, wb[0]);
  load_wout(1, wb[1]);

  __syncthreads();  // barrier 2: waves done with private pool regions

  // ---- write O (all heads) into Os[32][520] overlaying pool ----
#pragma unroll
  for (int hh = 0; hh < 2; hh++) {
    int h = wave * 2 + hh;
#pragma unroll
    for (int mt = 0; mt < 2; mt++)
#pragma unroll
      for (int nt = 0; nt < 4; nt++)
#pragma unroll
        for (int rr = 0; rr < 4; rr++)
          Os[(mt * 16 + quad * 4 + rr) * 520 + h * 64 + nt * 16 + l16] = obf[hh][mt][nt][rr];
  }
  __syncthreads();  // barrier 3

  // ---- out = O @ W_out + b : 8 pipelined weight batches ----
  f32x4 outacc[4][2];
#pragma unroll
  for (int g = 0; g < 4; g++) { outacc[g][0] = zero; outacc[g][1] = zero; }
#pragma unroll
  for (int b = 0; b < 8; b++) {
    int g = b >> 1, kk0 = (b & 1) * 8;
#pragma unroll
    for (int j = 0; j < 8; j++) {
      int kk = kk0 + j;
      bf16x8 a0 = *(const bf16x8*)(&Os[l16 * 520 + kk * 32 + quad * 8]);
      bf16x8 a1 = *(const bf16x8*)(&Os[(16 + l16) * 520 + kk * 32 + quad * 8]);
      outacc[g][0] = mfma16(a0, wb[b & 1][j], outacc[g][0]);
      outacc[g][1] = mfma16(a1, wb[b & 1][j], outacc[g][1]);
    }
    if (b + 2 < 8) load_wout(b + 2, wb[b & 1]);  // distance-2, after last use
  }

  // ---- epilogue: bias + store (plain stores: let L2 merge 64B half-lines) ----
  float* og = out + (size_t)bp * 32 * 256;
#pragma unroll
  for (int g = 0; g < 4; g++) {
    int ntile = wave + g * 4;
    float bias = b_out[ntile * 16 + l16];
#pragma unroll
    for (int mt = 0; mt < 2; mt++) {
      f32x4 a = outacc[g][mt];
#pragma unroll
      for (int rr = 0; rr < 4; rr++)
        og[(mt * 16 + quad * 4 + rr) * 256 + ntile * 16 + l16] = a[rr] + bias;
    }
  }
}

extern "C" void kernel_launch(void* const* d_in, const int* in_sizes, int n_in,
                              void* d_out, int out_size, void* d_ws, size_t ws_size,
                              hipStream_t stream) {
  const float* x    = (const float*)d_in[0];
  const float* Wqkv = (const float*)d_in[1];
  const float* Wout = (const float*)d_in[2];
  const float* bout = (const float*)d_in[3];
  float* out = (float*)d_out;

  __bf16* WqkvP = (__bf16*)d_ws;
  __bf16* WoutP = (__bf16*)((char*)d_ws + (size_t)1536 * 256 * 2);

  prep_weights<<<256, 256, 0, stream>>>(Wqkv, Wout, WqkvP, WoutP);
  attn_fused<<<4096, 256, 0, stream>>>(x, WqkvP, WoutP, bout, out);
}

// Round 6
// 402.438 us; speedup vs baseline: 1.6143x; 1.0148x over previous
//
#include <hip/hip_runtime.h>

// Attention_37074157699274 : fused qkv-proj + 8-head attention (n=32,d=64) + out-proj
// R3: fragment-packed weights (coalesced 1KiB wave loads), distance-2 double-buffered
// weight prefetch, non-temporal x streaming to protect L2 weight residency.
// R4/R5: Xs overlays pool, vT tightened to [64][32] + in-row XOR swizzle.
// R6: revert launch_bounds to (256,2) — (256,3) caused an 84-VGPR spill catastrophe.
//     Result: LDS 53248 did NOT give 3 blocks/CU (occupancy stuck at 22.6%).
// R7: LDS-granule theory — alloc granule appears to be 8 KiB (74240->81920: 2 fit;
//     53248->57344: 3*57344 > 160K, still 2). Cut to 48 KiB exactly: qs/ks from
//     padded [32][72] to XOR-swizzled [32][64] (phys = r*64 + (c&7) +
//     (((c>>3)^(r&7))<<3)). 16B reads stay aligned, 8 lanes/16B-slot = bank floor.
//     4 waves * 6144 ele * 2B = 49152 B -> 3 blocks/CU (6 granules * 3 = 18 <= 20).
// R8/R9: resubmits of R7 — rounds 4 and 5 died on container infrastructure
//     (acquisition-level error, no compile/test output; kernel never executed).
//     Source has no divergent barriers / unbounded loops; identical grid & ws as
//     the passing R6 run. Theory and predictions unchanged.

typedef __bf16 bf16x8 __attribute__((ext_vector_type(8)));
typedef __bf16 bf16x4 __attribute__((ext_vector_type(4)));
typedef float f32x4 __attribute__((ext_vector_type(4)));
typedef float f32x4v __attribute__((ext_vector_type(4)));

__device__ __forceinline__ f32x4 mfma16(bf16x8 a, bf16x8 b, f32x4 c) {
  return __builtin_amdgcn_mfma_f32_16x16x32_bf16(a, b, c, 0, 0, 0);
}

// ws: [0,786432) WqkvP bf16 packed frags ; [786432,1048576) WoutP bf16 packed frags
// WqkvP: frag t = (combo*8 + kk)*64 + lane, combo = (mat*8+h)*4+nt, 8 ele each:
//   ele j = Wqkv[k][n], n = mat*512+h*64+nt*16+(lane&15), k = kk*32+(lane>>4)*8+j
// WoutP: frag t = (ntile*16 + kk)*64 + lane:
//   ele j = Wout[k][n], n = ntile*16+(lane&15), k = kk*32+(lane>>4)*8+j
__global__ __launch_bounds__(256) void prep_weights(const float* __restrict__ Wqkv,
                                                    const float* __restrict__ Wout,
                                                    __bf16* __restrict__ WqkvP,
                                                    __bf16* __restrict__ WoutP) {
  int t = blockIdx.x * 256 + threadIdx.x;
  if (t < 49152) {
    int lane = t & 63, rest = t >> 6;
    int kk = rest & 7, combo = rest >> 3;
    int nt = combo & 3, mh = combo >> 2;
    int h = mh & 7, mat = mh >> 3;
    int l16 = lane & 15, quad = lane >> 4;
    int n = mat * 512 + h * 64 + nt * 16 + l16;
    int k0 = kk * 32 + quad * 8;
    __bf16* dst = WqkvP + (size_t)t * 8;
#pragma unroll
    for (int j = 0; j < 8; j++) dst[j] = (__bf16)Wqkv[(size_t)(k0 + j) * 1536 + n];
  }
  int t2 = t - 49152;
  if (t2 >= 0 && t2 < 16384) {
    int lane = t2 & 63, rest = t2 >> 6;
    int kk = rest & 15, ntile = rest >> 4;
    int l16 = lane & 15, quad = lane >> 4;
    int n = ntile * 16 + l16;
    int k0 = kk * 32 + quad * 8;
    __bf16* dst = WoutP + (size_t)t2 * 8;
#pragma unroll
    for (int j = 0; j < 8; j++) dst[j] = (__bf16)Wout[(size_t)(k0 + j) * 256 + n];
  }
}

__global__ __launch_bounds__(256, 2) void attn_fused(const float* __restrict__ x,
                                                     const __bf16* __restrict__ WqkvP,
                                                     const __bf16* __restrict__ WoutP,
                                                     const float* __restrict__ b_out,
                                                     float* __restrict__ out) {
  // Single pool, 49152 B total (48 KiB = 6x8KiB granules) -> 3 blocks/CU.
  // Phase A (staging):   Xs overlay [32][264] = 8448 ele
  // Phase B (attention): per-wave {qs[32][64] swz, ks[32][64] swz, vT[64][32] swz} = 6144 ele
  // Phase C (out-proj):  Os overlay [32][520] = 16640 ele
  __shared__ __align__(16) __bf16 pool[4 * 6144];

  const int tid  = threadIdx.x;
  const int wave = tid >> 6;
  const int lane = tid & 63;
  const int quad = lane >> 4;
  const int l16  = lane & 15;
  const int bp   = blockIdx.x;

  __bf16* qs = pool + wave * 6144;  // [32][64] swizzled (reused as P scratch)
  __bf16* ks = qs + 2048;           // [32][64] swizzled
  __bf16* vT = ks + 2048;           // [64][32] v transposed, XOR-swizzled
  __bf16* Xs = pool;                // [32][264] staging overlay (dead after hoist)
  __bf16* Os = pool;                // [32][520] after barrier 2 (overlays pool)

  // ---- stage X tile -> LDS bf16 (non-temporal: read-once stream) ----
  const f32x4v* xg = (const f32x4v*)(x + (size_t)bp * 32 * 256);
  for (int i = tid; i < 32 * 64; i += 256) {
    int row = i >> 6, c4 = i & 63;
    f32x4v v = __builtin_nontemporal_load(xg + i);
    bf16x4 pk;
    pk[0] = (__bf16)v[0]; pk[1] = (__bf16)v[1]; pk[2] = (__bf16)v[2]; pk[3] = (__bf16)v[3];
    *(bf16x4*)(&Xs[row * 264 + c4 * 4]) = pk;
  }
  __syncthreads();  // barrier 1: Xs staged

  // ---- weight-fragment load helpers (each: 8 perfectly-coalesced 1KiB wave loads) ----
  bf16x8 bb[2][8];
  auto load_qkv = [&](int c, bf16x8* dst) {
    int hloc = wave * 2 + (c >= 12 ? 1 : 0);
    int r = (c >= 12) ? c - 12 : c;
    int mat = r >> 2, nt = r & 3;
    const __bf16* base = WqkvP + ((size_t)((mat * 8 + hloc) * 4 + nt)) * 4096 + lane * 8;
#pragma unroll
    for (int kk = 0; kk < 8; kk++) dst[kk] = *(const bf16x8*)(base + kk * 512);
  };

  load_qkv(0, bb[0]);
  load_qkv(1, bb[1]);

  // ---- hoist X A-fragments (reused by all 24 qkv combos) ----
  bf16x8 xa0[8], xa1[8];
#pragma unroll
  for (int kk = 0; kk < 8; kk++) {
    xa0[kk] = *(const bf16x8*)(&Xs[l16 * 264 + kk * 32 + quad * 8]);
    xa1[kk] = *(const bf16x8*)(&Xs[(16 + l16) * 264 + kk * 32 + quad * 8]);
  }
  __syncthreads();  // barrier 1b: all waves done reading Xs before pool is overwritten

  const f32x4 zero = {0.f, 0.f, 0.f, 0.f};
  // qs/ks swizzle: logical (r,c) -> phys r*64 + (c&7) + (((c>>3) ^ (r&7)) << 3).
  // In the unrolled loops the XOR folds to compile-time-rr/nt plus these hoisted terms:
  const int A7 = l16 & 7;          // c&7 for write cols nt*16+l16; r&7 for read rows l16
  const int B1 = l16 >> 3;         // (c>>3) low bit from l16
  const int Q4 = (quad & 1) << 2;  // (r&7) contribution of write rows quad*4+rr
  // vT XOR-swizzle term: ((row>>1)&3)<<3 with row = nt*16+l16 == ((l16>>1)&3)<<3.
  const int vswz = ((l16 >> 1) & 3) << 3;
  bf16x4 obf[2][2][4];  // O output [hh][mt][nt] in regs until Os write

#pragma unroll
  for (int hh = 0; hh < 2; hh++) {
#pragma unroll
    for (int r = 0; r < 12; r++) {
      const int c = hh * 12 + r;
      const int mat = r >> 2, nt = r & 3;
      f32x4 a0 = zero, a1 = zero;
#pragma unroll
      for (int kk = 0; kk < 8; kk++) {
        a0 = mfma16(xa0[kk], bb[c & 1][kk], a0);
        a1 = mfma16(xa1[kk], bb[c & 1][kk], a1);
      }
      if (c + 2 < 24) load_qkv(c + 2, bb[c & 1]);  // distance-2 prefetch (after last use)
      if (mat == 0) {  // q — fold softmax scale 1/8
#pragma unroll
        for (int rr = 0; rr < 4; rr++) {
          int pc = A7 + (((nt * 2) ^ B1 ^ Q4 ^ rr) << 3);  // swizzled col
          qs[(quad * 4 + rr) * 64 + pc]      = (__bf16)(a0[rr] * 0.125f);
          qs[(16 + quad * 4 + rr) * 64 + pc] = (__bf16)(a1[rr] * 0.125f);
        }
      } else if (mat == 1) {
#pragma unroll
        for (int rr = 0; rr < 4; rr++) {
          int pc = A7 + (((nt * 2) ^ B1 ^ Q4 ^ rr) << 3);
          ks[(quad * 4 + rr) * 64 + pc]      = (__bf16)a0[rr];
          ks[(16 + quad * 4 + rr) * 64 + pc] = (__bf16)a1[rr];
        }
      } else {  // v transposed: vT[d][token], token cols XOR-swizzled by ((d>>1)&3)<<3
        bf16x4 p0, p1;
#pragma unroll
        for (int rr = 0; rr < 4; rr++) { p0[rr] = (__bf16)a0[rr]; p1[rr] = (__bf16)a1[rr]; }
        int rb = (nt * 16 + l16) * 32;
        *(bf16x4*)(&vT[rb + ((quad * 4) ^ vswz)])      = p0;
        *(bf16x4*)(&vT[rb + ((16 + quad * 4) ^ vswz)]) = p1;
      }
    }

    // ---- S = q @ k^T (scale folded into q), wave-private ----
    // Read rows l16 / 16+l16 (r&7 = A7), logical col8 = kk*4+quad -> phys slot ^A7.
    f32x4 s[2][2] = {{zero, zero}, {zero, zero}};
#pragma unroll
    for (int kk = 0; kk < 2; kk++) {
      int sl = ((kk * 4) ^ quad ^ A7) << 3;
      bf16x8 a0 = *(const bf16x8*)(&qs[l16 * 64 + sl]);
      bf16x8 a1 = *(const bf16x8*)(&qs[(16 + l16) * 64 + sl]);
      bf16x8 b0 = *(const bf16x8*)(&ks[l16 * 64 + sl]);
      bf16x8 b1 = *(const bf16x8*)(&ks[(16 + l16) * 64 + sl]);
      s[0][0] = mfma16(a0, b0, s[0][0]);
      s[0][1] = mfma16(a0, b1, s[0][1]);
      s[1][0] = mfma16(a1, b0, s[1][0]);
      s[1][1] = mfma16(a1, b1, s[1][1]);
    }

    // ---- in-register softmax: row i lives in the 16 lanes of one quad ----
    float mx[2][4], sm[2][4], e[2][2][4];
#pragma unroll
    for (int mt = 0; mt < 2; mt++)
#pragma unroll
      for (int rr = 0; rr < 4; rr++) mx[mt][rr] = fmaxf(s[mt][0][rr], s[mt][1][rr]);
#pragma unroll
    for (int mask = 1; mask < 16; mask <<= 1)
#pragma unroll
      for (int mt = 0; mt < 2; mt++)
#pragma unroll
        for (int rr = 0; rr < 4; rr++) mx[mt][rr] = fmaxf(mx[mt][rr], __shfl_xor(mx[mt][rr], mask));
#pragma unroll
    for (int mt = 0; mt < 2; mt++)
#pragma unroll
      for (int rr = 0; rr < 4; rr++) {
        e[mt][0][rr] = __expf(s[mt][0][rr] - mx[mt][rr]);
        e[mt][1][rr] = __expf(s[mt][1][rr] - mx[mt][rr]);
        sm[mt][rr] = e[mt][0][rr] + e[mt][1][rr];
      }
#pragma unroll
    for (int mask = 1; mask < 16; mask <<= 1)
#pragma unroll
      for (int mt = 0; mt < 2; mt++)
#pragma unroll
        for (int rr = 0; rr < 4; rr++) sm[mt][rr] += __shfl_xor(sm[mt][rr], mask);

    // ---- P -> LDS (C-layout, reuse qs; qs fully consumed above) -> reread in A-layout ----
#pragma unroll
    for (int mt = 0; mt < 2; mt++) {
      float inv0 = 1.f / sm[mt][0], inv1 = 1.f / sm[mt][1], inv2 = 1.f / sm[mt][2], inv3 = 1.f / sm[mt][3];
#pragma unroll
      for (int nt = 0; nt < 2; nt++) {
#pragma unroll
        for (int rr = 0; rr < 4; rr++) {
          int pc = A7 + (((nt * 2) ^ B1 ^ Q4 ^ rr) << 3);
          float inv = (rr == 0) ? inv0 : (rr == 1) ? inv1 : (rr == 2) ? inv2 : inv3;
          qs[(mt * 16 + quad * 4 + rr) * 64 + pc] = (__bf16)(e[mt][nt][rr] * inv);
        }
      }
    }
    bf16x8 pa0 = *(const bf16x8*)(&qs[l16 * 64 + ((quad ^ A7) << 3)]);
    bf16x8 pa1 = *(const bf16x8*)(&qs[(16 + l16) * 64 + ((quad ^ A7) << 3)]);

    // ---- O = P @ v ----
#pragma unroll
    for (int nt = 0; nt < 4; nt++) {
      bf16x8 b = *(const bf16x8*)(&vT[(nt * 16 + l16) * 32 + ((quad * 8) ^ vswz)]);
      f32x4 o0 = mfma16(pa0, b, zero);
      f32x4 o1 = mfma16(pa1, b, zero);
#pragma unroll
      for (int rr = 0; rr < 4; rr++) {
        obf[hh][0][nt][rr] = (__bf16)o0[rr];
        obf[hh][1][nt][rr] = (__bf16)o1[rr];
      }
    }
  }

  // ---- prefetch first two out-proj weight batches before the barriers ----
  bf16x8 wb[2][8];
  auto load_wout = [&](int b, bf16x8* dst) {
    int g = b >> 1, ntile = wave + g * 4, kk0 = (b & 1) * 8;
    const __bf16* base = WoutP + ((size_t)(ntile * 16 + kk0) * 64 + lane) * 8;
#pragma unroll
    for (int j = 0; j < 8; j++) dst[j] = *(const bf16x8*)(base + j * 512);
  };
  load_wout(0, wb[0]);
  load_wout(1, wb[1]);

  __syncthreads();  // barrier 2: waves done with private pool regions

  // ---- write O (all heads) into Os[32][520] overlaying pool ----
#pragma unroll
  for (int hh = 0; hh < 2; hh++) {
    int h = wave * 2 + hh;
#pragma unroll
    for (int mt = 0; mt < 2; mt++)
#pragma unroll
      for (int nt = 0; nt < 4; nt++)
#pragma unroll
        for (int rr = 0; rr < 4; rr++)
          Os[(mt * 16 + quad * 4 + rr) * 520 + h * 64 + nt * 16 + l16] = obf[hh][mt][nt][rr];
  }
  __syncthreads();  // barrier 3

  // ---- out = O @ W_out + b : 8 pipelined weight batches ----
  f32x4 outacc[4][2];
#pragma unroll
  for (int g = 0; g < 4; g++) { outacc[g][0] = zero; outacc[g][1] = zero; }
#pragma unroll
  for (int b = 0; b < 8; b++) {
    int g = b >> 1, kk0 = (b & 1) * 8;
#pragma unroll
    for (int j = 0; j < 8; j++) {
      int kk = kk0 + j;
      bf16x8 a0 = *(const bf16x8*)(&Os[l16 * 520 + kk * 32 + quad * 8]);
      bf16x8 a1 = *(const bf16x8*)(&Os[(16 + l16) * 520 + kk * 32 + quad * 8]);
      outacc[g][0] = mfma16(a0, wb[b & 1][j], outacc[g][0]);
      outacc[g][1] = mfma16(a1, wb[b & 1][j], outacc[g][1]);
    }
    if (b + 2 < 8) load_wout(b + 2, wb[b & 1]);  // distance-2, after last use
  }

  // ---- epilogue: bias + store (plain stores: let L2 merge 64B half-lines) ----
  float* og = out + (size_t)bp * 32 * 256;
#pragma unroll
  for (int g = 0; g < 4; g++) {
    int ntile = wave + g * 4;
    float bias = b_out[ntile * 16 + l16];
#pragma unroll
    for (int mt = 0; mt < 2; mt++) {
      f32x4 a = outacc[g][mt];
#pragma unroll
      for (int rr = 0; rr < 4; rr++)
        og[(mt * 16 + quad * 4 + rr) * 256 + ntile * 16 + l16] = a[rr] + bias;
    }
  }
}

extern "C" void kernel_launch(void* const* d_in, const int* in_sizes, int n_in,
                              void* d_out, int out_size, void* d_ws, size_t ws_size,
                              hipStream_t stream) {
  const float* x    = (const float*)d_in[0];
  const float* Wqkv = (const float*)d_in[1];
  const float* Wout = (const float*)d_in[2];
  const float* bout = (const float*)d_in[3];
  float* out = (float*)d_out;

  __bf16* WqkvP = (__bf16*)d_ws;
  __bf16* WoutP = (__bf16*)((char*)d_ws + (size_t)1536 * 256 * 2);

  prep_weights<<<256, 256, 0, stream>>>(Wqkv, Wout, WqkvP, WoutP);
  attn_fused<<<4096, 256, 0, stream>>>(x, WqkvP, WoutP, bout, out);
}